// Round 13
// baseline (313.923 us; speedup 1.0000x reference)
//
#include <hip/hip_runtime.h>
#include <hip/hip_bf16.h>
#include <math.h>

// Problem constants
#define D_MODEL 256
#define DEPTH 2
#define D_INNER 512
#define D_STATE 16
#define D_CONV 4
#define DT_RANK 16
#define BATCH 2
#define SEQLEN 2048
#define MROWS (BATCH * SEQLEN)   // 4096

#define LCH 8     // rows per chunk
#define CCH 256   // chunks per batch-sequence
#define NCHUNK (BATCH * CCH)   // 512 blocks -> 2 blocks/CU

typedef __attribute__((ext_vector_type(8))) short bf16x8;
typedef __attribute__((ext_vector_type(4))) float f32x4;

__device__ __forceinline__ float silu(float v) {
    return v / (1.0f + __expf(-v));
}

__device__ __forceinline__ ushort f2bf(float f) {
    union { float f; unsigned u; } v; v.f = f;
    unsigned r = v.u + 0x7FFFu + ((v.u >> 16) & 1u);
    return (ushort)(r >> 16);
}

__device__ __forceinline__ float bf2f(ushort u) {
    union { unsigned u; float f; } v; v.u = ((unsigned)u) << 16;
    return v.f;
}

#define HS_STR 264   // ushort stride, 16-row bf16 LN output (rows 11-15 pad)
#define XC_STR 520   // ushort stride, xc/yy LDS tiles (rows 8-15 pad)

// ---------------------------------------------------------------------------
// k_cvt: all three weight tensors f32 -> bf16 in one dispatch (grid 512x256).
// ---------------------------------------------------------------------------
__global__ __launch_bounds__(256) void k_cvt(
    const float* __restrict__ ipw, const float* __restrict__ xpw,
    const float* __restrict__ opw, ushort* __restrict__ ipwB,
    ushort* __restrict__ xpwB, ushort* __restrict__ opwB)
{
    size_t tid = (size_t)blockIdx.x * 256 + threadIdx.x;
    {
        float4 v = ((const float4*)ipw)[tid];
        ushort4 o = { f2bf(v.x), f2bf(v.y), f2bf(v.z), f2bf(v.w) };
        ((ushort4*)ipwB)[tid] = o;
    }
    if (tid < 12288) {
        float4 v = ((const float4*)xpw)[tid];
        ushort4 o = { f2bf(v.x), f2bf(v.y), f2bf(v.z), f2bf(v.w) };
        ((ushort4*)xpwB)[tid] = o;
    }
    if (tid < 65536) {
        float4 v = ((const float4*)opw)[tid];
        ushort4 o = { f2bf(v.x), f2bf(v.y), f2bf(v.z), f2bf(v.w) };
        ((ushort4*)opwB)[tid] = o;
    }
}

// ---------------------------------------------------------------------------
// k_front: LN (11 rows, register-held) + in_proj MFMA (one 16-row tile,
// halo included, tail rows discarded) + conv + SiLU + x_proj MFMA +
// scan_sum, per 8-row chunk. Grid 512 x 512 -> 2 blocks/CU.
// ---------------------------------------------------------------------------
__global__ __launch_bounds__(512) void k_front(
    const float* __restrict__ xin, const float* __restrict__ lnwL,
    const float* __restrict__ lnbL, const ushort* __restrict__ ipwL,
    const float* __restrict__ cwL, const float* __restrict__ cbL,
    const ushort* __restrict__ xpwL, const float* __restrict__ dpwL,
    const float* __restrict__ dpbL, const float* __restrict__ alogL,
    ushort* __restrict__ zsB, ushort* __restrict__ xcB,
    float* __restrict__ dbl, float* __restrict__ Ssum,
    float* __restrict__ sdsum)
{
    const int t = threadIdx.x, bid = blockIdx.x;
    const int lane = t & 63, w = t >> 6, l15 = lane & 15, quad = lane >> 4;
    __shared__ ushort hs[16 * HS_STR];     //  8.4 KB (rows = m0-3 .. m0+12)
    __shared__ ushort xi_s[11 * 512];      // 11.0 KB (rows m0-3 .. m0+7)
    __shared__ ushort xc_s[16 * XC_STR];   // 16.6 KB (rows 0..7 valid)
    __shared__ float  dbl_s[8 * 52];       //  1.6 KB
    int m0 = bid * LCH;

    // ---- LayerNorm, 11 rows x 16 threads, values in registers ----
    if (t < 11 * 16) {
        int r = t >> 4, ci = t & 15;
        int grow = m0 - 3 + r; if (grow < 0) grow = 0;
        const float* xp = xin + (size_t)grow * D_MODEL + ci * 16;
        float v[16];
        *(float4*)&v[0]  = *(const float4*)(xp + 0);
        *(float4*)&v[4]  = *(const float4*)(xp + 4);
        *(float4*)&v[8]  = *(const float4*)(xp + 8);
        *(float4*)&v[12] = *(const float4*)(xp + 12);
        float s = 0.f, sq = 0.f;
        #pragma unroll
        for (int k = 0; k < 16; k++) { s += v[k]; sq += v[k] * v[k]; }
        #pragma unroll
        for (int off = 1; off < 16; off <<= 1) {
            s  += __shfl_xor(s, off, 16);
            sq += __shfl_xor(sq, off, 16);
        }
        float mu  = s * (1.0f / 256.f);
        float var = sq * (1.0f / 256.f) - mu * mu;
        float rst = rsqrtf(var + 1e-5f);
        #pragma unroll
        for (int k = 0; k < 16; k++) {
            int c = ci * 16 + k;
            hs[r * HS_STR + c] = f2bf((v[k] - mu) * rst * lnwL[c] + lnbL[c]);
        }
    }
    __syncthreads();

    // ---- in_proj MFMA: 8 waves x 8 n-tiles; rows m0-3..m0+12, tail junk --
    #pragma unroll
    for (int f = 0; f < 8; f++) {
        int n = w * 128 + f * 16 + l15;
        f32x4 acc = (f32x4){0.f, 0.f, 0.f, 0.f};
        for (int k0 = 0; k0 < D_MODEL; k0 += 32) {
            bf16x8 af = *(const bf16x8*)&hs[l15 * HS_STR + quad * 8 + k0];
            bf16x8 bw = *(const bf16x8*)(ipwL + (size_t)n * D_MODEL + quad * 8 + k0);
            acc = __builtin_amdgcn_mfma_f32_16x16x32_bf16(af, bw, acc, 0, 0, 0);
        }
        #pragma unroll
        for (int r2 = 0; r2 < 4; r2++) {
            int rl = quad * 4 + r2;              // row = m0-3+rl
            if (n < 512) {
                if (rl < 11) xi_s[rl * 512 + n] = f2bf(acc[r2]);
            } else {
                if (rl >= 3 && rl < 11)
                    zsB[(size_t)(m0 + rl - 3) * D_INNER + (n - 512)] =
                        f2bf(silu(acc[r2]));
            }
        }
    }
    __syncthreads();

    // ---- conv(4) + SiLU -> xc_s + xcB. d = t, 8 rows ----
    {
        float4 cw4 = *(const float4*)(cwL + t * 4);
        float cbv = cbL[t];
        #pragma unroll
        for (int rl = 0; rl < LCH; rl++) {
            int l = (m0 + rl) & (SEQLEN - 1);
            float s = cbv;
            if (l >= 3) s = fmaf(cw4.x, bf2f(xi_s[(rl + 0) * 512 + t]), s);
            if (l >= 2) s = fmaf(cw4.y, bf2f(xi_s[(rl + 1) * 512 + t]), s);
            if (l >= 1) s = fmaf(cw4.z, bf2f(xi_s[(rl + 2) * 512 + t]), s);
            s = fmaf(cw4.w, bf2f(xi_s[(rl + 3) * 512 + t]), s);
            ushort xcv = f2bf(silu(s));
            xc_s[rl * XC_STR + t] = xcv;
            xcB[(size_t)(m0 + rl) * D_INNER + t] = xcv;
        }
    }
    __syncthreads();

    // ---- x_proj MFMA (waves 0..2); A rows 8..15 junk, outputs discarded --
    if (w < 3) {
        f32x4 acc = (f32x4){0.f, 0.f, 0.f, 0.f};
        for (int k0 = 0; k0 < D_INNER; k0 += 32) {
            bf16x8 af = *(const bf16x8*)&xc_s[l15 * XC_STR + quad * 8 + k0];
            bf16x8 bw = *(const bf16x8*)(xpwL + (size_t)(w * 16 + l15) * D_INNER + quad * 8 + k0);
            acc = __builtin_amdgcn_mfma_f32_16x16x32_bf16(af, bw, acc, 0, 0, 0);
        }
        int n = w * 16 + l15;
        #pragma unroll
        for (int r2 = 0; r2 < 4; r2++) {
            int rl = quad * 4 + r2;
            if (rl < LCH) {
                dbl_s[rl * 52 + n] = acc[r2];
                dbl[(size_t)(m0 + rl) * 48 + n] = acc[r2];
            }
        }
    }
    __syncthreads();

    // ---- scan_sum: d = t, 8 steps, 16 states, delta inline ----
    {
        float a[16], wdp[16];
        #pragma unroll
        for (int n = 0; n < 16; n++) a[n] = -__expf(alogL[(size_t)t * 16 + n]);
        *(float4*)&wdp[0]  = *(const float4*)(dpwL + (size_t)t * 16 + 0);
        *(float4*)&wdp[4]  = *(const float4*)(dpwL + (size_t)t * 16 + 4);
        *(float4*)&wdp[8]  = *(const float4*)(dpwL + (size_t)t * 16 + 8);
        *(float4*)&wdp[12] = *(const float4*)(dpwL + (size_t)t * 16 + 12);
        float bias = dpbL[t];
        float h[16];
        #pragma unroll
        for (int n = 0; n < 16; n++) h[n] = 0.f;
        float sd = 0.f;
        for (int j = 0; j < LCH; j++) {
            const float* dp = &dbl_s[j * 52];
            float dot = bias;
            #pragma unroll
            for (int r2 = 0; r2 < 16; r2++) dot = fmaf(dp[r2], wdp[r2], dot);
            float dl = (dot > 20.f) ? dot : log1pf(__expf(dot));
            float xv = bf2f(xc_s[j * XC_STR + t]);
            float u = dl * xv;
            sd += dl;
            #pragma unroll
            for (int n = 0; n < 16; n++)
                h[n] = fmaf(__expf(dl * a[n]), h[n], dp[16 + n] * u);
        }
        size_t sbase = ((size_t)bid * 16) * D_INNER + t;
        #pragma unroll
        for (int n = 0; n < 16; n++) Ssum[sbase + (size_t)n * D_INNER] = h[n];
        sdsum[(size_t)bid * D_INNER + t] = sd;
    }
}

// ---------------------------------------------------------------------------
// k_comb: in-place exclusive prefix over 256 chunk summaries. Grid 64.
// ---------------------------------------------------------------------------
__global__ __launch_bounds__(256) void k_comb(
    const float* __restrict__ alogL, const float* __restrict__ sdsum,
    float* __restrict__ Ssum)
{
    const int t = threadIdx.x, bid = blockIdx.x;
    int dt2 = bid & 1;
    int n   = (bid >> 1) & 15;
    int b   = bid >> 5;
    int d   = dt2 * 256 + t;
    float a = -__expf(alogL[(size_t)d * 16 + n]);
    float hi = 0.f;
    #pragma unroll 4
    for (int c = 0; c < CCH; c++) {
        size_t idx = ((size_t)(b * CCH + c) * 16 + n) * D_INNER + d;
        float s  = Ssum[idx];
        float sd = sdsum[(size_t)(b * CCH + c) * D_INNER + d];
        Ssum[idx] = hi;
        hi = fmaf(__expf(a * sd), hi, s);
    }
}

// ---------------------------------------------------------------------------
// k_back: rescan (8 steps, delta inline) + D-skip + SiLU(z) gate (yy in
// LDS) + out_proj MFMA + residual. Grid 512 x 512 -> 2 blocks/CU.
// ---------------------------------------------------------------------------
__global__ __launch_bounds__(512) void k_back(
    const float* __restrict__ dbl, const ushort* __restrict__ xcB,
    const ushort* __restrict__ zsB, const float* __restrict__ Ssum,
    const float* __restrict__ dpwL, const float* __restrict__ dpbL,
    const float* __restrict__ alogL, const float* __restrict__ dparL,
    const ushort* __restrict__ opwL, const float* __restrict__ xin,
    float* __restrict__ xout)
{
    const int t = threadIdx.x, bid = blockIdx.x;
    const int lane = t & 63, w = t >> 6, l15 = lane & 15, quad = lane >> 4;
    __shared__ ushort yy_s[16 * XC_STR];   // rows 0..7 valid, 8..15 junk
    int m0 = bid * LCH;

    // ---- rescan, d = t ----
    {
        float a[16], wdp[16];
        #pragma unroll
        for (int n = 0; n < 16; n++) a[n] = -__expf(alogL[(size_t)t * 16 + n]);
        *(float4*)&wdp[0]  = *(const float4*)(dpwL + (size_t)t * 16 + 0);
        *(float4*)&wdp[4]  = *(const float4*)(dpwL + (size_t)t * 16 + 4);
        *(float4*)&wdp[8]  = *(const float4*)(dpwL + (size_t)t * 16 + 8);
        *(float4*)&wdp[12] = *(const float4*)(dpwL + (size_t)t * 16 + 12);
        float bias = dpbL[t];
        float Dd = dparL[t];
        float h[16];
        size_t sbase = ((size_t)bid * 16) * D_INNER + t;
        #pragma unroll
        for (int n = 0; n < 16; n++) h[n] = Ssum[sbase + (size_t)n * D_INNER];
        for (int j = 0; j < LCH; j++) {
            int row = m0 + j;
            const float* dp = dbl + (size_t)row * 48;
            float dtv[16], Bv[16], Cv[16];
            *(float4*)&dtv[0]  = *(const float4*)(dp + 0);
            *(float4*)&dtv[4]  = *(const float4*)(dp + 4);
            *(float4*)&dtv[8]  = *(const float4*)(dp + 8);
            *(float4*)&dtv[12] = *(const float4*)(dp + 12);
            *(float4*)&Bv[0]   = *(const float4*)(dp + 16);
            *(float4*)&Bv[4]   = *(const float4*)(dp + 20);
            *(float4*)&Bv[8]   = *(const float4*)(dp + 24);
            *(float4*)&Bv[12]  = *(const float4*)(dp + 28);
            *(float4*)&Cv[0]   = *(const float4*)(dp + 32);
            *(float4*)&Cv[4]   = *(const float4*)(dp + 36);
            *(float4*)&Cv[8]   = *(const float4*)(dp + 40);
            *(float4*)&Cv[12]  = *(const float4*)(dp + 44);
            float dot = bias;
            #pragma unroll
            for (int r2 = 0; r2 < 16; r2++) dot = fmaf(dtv[r2], wdp[r2], dot);
            float dl = (dot > 20.f) ? dot : log1pf(__expf(dot));
            float xv = bf2f(xcB[(size_t)row * D_INNER + t]);
            float gate = bf2f(zsB[(size_t)row * D_INNER + t]);
            float u = dl * xv;
            float y0 = 0.f, y1 = 0.f, y2 = 0.f, y3 = 0.f;
            #pragma unroll
            for (int n = 0; n < 16; n += 4) {
                h[n + 0] = fmaf(__expf(dl * a[n + 0]), h[n + 0], Bv[n + 0] * u);
                h[n + 1] = fmaf(__expf(dl * a[n + 1]), h[n + 1], Bv[n + 1] * u);
                h[n + 2] = fmaf(__expf(dl * a[n + 2]), h[n + 2], Bv[n + 2] * u);
                h[n + 3] = fmaf(__expf(dl * a[n + 3]), h[n + 3], Bv[n + 3] * u);
                y0 = fmaf(h[n + 0], Cv[n + 0], y0);
                y1 = fmaf(h[n + 1], Cv[n + 1], y1);
                y2 = fmaf(h[n + 2], Cv[n + 2], y2);
                y3 = fmaf(h[n + 3], Cv[n + 3], y3);
            }
            float y = (y0 + y1) + (y2 + y3) + xv * Dd;
            yy_s[j * XC_STR + t] = f2bf(y * gate);
        }
    }
    __syncthreads();

    // ---- out_proj MFMA + residual: 8 waves x 2 n-tiles; rows 8-15 junk --
    #pragma unroll
    for (int f = 0; f < 2; f++) {
        int n = w * 32 + f * 16 + l15;
        f32x4 acc = (f32x4){0.f, 0.f, 0.f, 0.f};
        for (int k0 = 0; k0 < D_INNER; k0 += 32) {
            bf16x8 af = *(const bf16x8*)&yy_s[l15 * XC_STR + quad * 8 + k0];
            bf16x8 bw = *(const bf16x8*)(opwL + (size_t)n * D_INNER + quad * 8 + k0);
            acc = __builtin_amdgcn_mfma_f32_16x16x32_bf16(af, bw, acc, 0, 0, 0);
        }
        #pragma unroll
        for (int r2 = 0; r2 < 4; r2++) {
            int rl = quad * 4 + r2;
            if (rl < LCH) {
                int row = m0 + rl;
                xout[(size_t)row * D_MODEL + n] =
                    acc[r2] + xin[(size_t)row * D_MODEL + n];
            }
        }
    }
}

// ---------------------------------------------------------------------------
// Launch
// ---------------------------------------------------------------------------
extern "C" void kernel_launch(void* const* d_in, const int* in_sizes, int n_in,
                              void* d_out, int out_size, void* d_ws, size_t ws_size,
                              hipStream_t stream)
{
    const float* x    = (const float*)d_in[0];
    const float* lnw  = (const float*)d_in[1];
    const float* lnb  = (const float*)d_in[2];
    const float* ipw  = (const float*)d_in[3];
    const float* cw   = (const float*)d_in[4];
    const float* cb   = (const float*)d_in[5];
    const float* xpw  = (const float*)d_in[6];
    const float* dpw  = (const float*)d_in[7];
    const float* dpb  = (const float*)d_in[8];
    const float* alog = (const float*)d_in[9];
    const float* dpar = (const float*)d_in[10];
    const float* opw  = (const float*)d_in[11];
    float* out = (float*)d_out;

    char* p = (char*)d_ws;
    auto alloc = [&](size_t bytes) { char* r = p; p += (bytes + 255) & ~(size_t)255; return r; };
    ushort* zsB   = (ushort*)alloc((size_t)MROWS * D_INNER * 2);
    ushort* xcB   = (ushort*)alloc((size_t)MROWS * D_INNER * 2);
    float*  dbl   = (float*)alloc((size_t)MROWS * 48 * 4);
    float*  Ssum  = (float*)alloc((size_t)NCHUNK * 16 * D_INNER * 4);
    float*  sdsum = (float*)alloc((size_t)NCHUNK * D_INNER * 4);
    float*  xbuf  = (float*)alloc((size_t)MROWS * D_MODEL * 4);
    ushort* ipwB  = (ushort*)alloc((size_t)DEPTH * 2 * D_INNER * D_MODEL * 2);
    ushort* xpwB  = (ushort*)alloc((size_t)DEPTH * 48 * D_INNER * 2);
    ushort* opwB  = (ushort*)alloc((size_t)DEPTH * D_MODEL * D_INNER * 2);

    k_cvt<<<512, 256, 0, stream>>>(ipw, xpw, opw, ipwB, xpwB, opwB);

    for (int lyr = 0; lyr < DEPTH; lyr++) {
        const float* xin = (lyr == 0) ? x : xbuf;
        float* xout = (lyr == DEPTH - 1) ? out : xbuf;
        const float* alogL = alog + (size_t)lyr * D_INNER * D_STATE;
        const float* dpwL  = dpw + (size_t)lyr * D_INNER * DT_RANK;
        const float* dpbL  = dpb + lyr * D_INNER;

        k_front<<<NCHUNK, 512, 0, stream>>>(
            xin, lnw + lyr * D_MODEL, lnb + lyr * D_MODEL,
            ipwB + (size_t)lyr * 2 * D_INNER * D_MODEL,
            cw + (size_t)lyr * D_INNER * D_CONV, cb + lyr * D_INNER,
            xpwB + (size_t)lyr * 48 * D_INNER, dpwL, dpbL, alogL,
            zsB, xcB, dbl, Ssum, sdsum);

        k_comb<<<64, 256, 0, stream>>>(alogL, sdsum, Ssum);

        k_back<<<NCHUNK, 512, 0, stream>>>(
            dbl, xcB, zsB, Ssum, dpwL, dpbL, alogL,
            dpar + lyr * D_INNER,
            opwB + (size_t)lyr * D_MODEL * D_INNER, xin, xout);
    }
}

// Round 14
// 260.945 us; speedup vs baseline: 1.2030x; 1.2030x over previous
//
#include <hip/hip_runtime.h>
#include <hip/hip_bf16.h>
#include <math.h>

// Problem constants
#define D_MODEL 256
#define DEPTH 2
#define D_INNER 512
#define D_STATE 16
#define D_CONV 4
#define DT_RANK 16
#define BATCH 2
#define SEQLEN 2048
#define MROWS (BATCH * SEQLEN)   // 4096

#define CCH 128   // chunks per batch-sequence
#define LCH 16    // rows per chunk

typedef __attribute__((ext_vector_type(8))) short bf16x8;
typedef __attribute__((ext_vector_type(4))) float f32x4;

__device__ __forceinline__ float silu(float v) {
    return v / (1.0f + __expf(-v));
}

__device__ __forceinline__ ushort f2bf(float f) {
    union { float f; unsigned u; } v; v.f = f;
    unsigned r = v.u + 0x7FFFu + ((v.u >> 16) & 1u);
    return (ushort)(r >> 16);
}

__device__ __forceinline__ float bf2f(ushort u) {
    union { unsigned u; float f; } v; v.u = ((unsigned)u) << 16;
    return v.f;
}

#define XS_STR 260   // f32 stride, 19-row LN tile
#define HS_STR 264   // ushort stride, 19-row bf16 LN output
#define XC_STR 520   // ushort stride, xc/yy LDS tiles (2-way conflicts max)

// ---------------------------------------------------------------------------
// k_cvt: all three weight tensors f32 -> bf16 in one dispatch (grid 512x256).
// ---------------------------------------------------------------------------
__global__ __launch_bounds__(256) void k_cvt(
    const float* __restrict__ ipw, const float* __restrict__ xpw,
    const float* __restrict__ opw, ushort* __restrict__ ipwB,
    ushort* __restrict__ xpwB, ushort* __restrict__ opwB)
{
    size_t tid = (size_t)blockIdx.x * 256 + threadIdx.x;
    {
        float4 v = ((const float4*)ipw)[tid];
        ushort4 o = { f2bf(v.x), f2bf(v.y), f2bf(v.z), f2bf(v.w) };
        ((ushort4*)ipwB)[tid] = o;
    }
    if (tid < 12288) {
        float4 v = ((const float4*)xpw)[tid];
        ushort4 o = { f2bf(v.x), f2bf(v.y), f2bf(v.z), f2bf(v.w) };
        ((ushort4*)xpwB)[tid] = o;
    }
    if (tid < 65536) {
        float4 v = ((const float4*)opw)[tid];
        ushort4 o = { f2bf(v.x), f2bf(v.y), f2bf(v.z), f2bf(v.w) };
        ((ushort4*)opwB)[tid] = o;
    }
}

// ---------------------------------------------------------------------------
// k_front: LN (19 rows incl. 3-row conv halo) + in_proj MFMA + conv + SiLU
//          + x_proj MFMA + scan_sum, per 16-row chunk. Grid 256 x 768.
// 12 waves: tile1 (waves 0-7, 8 f-loops) runs CONCURRENTLY with the halo
// tile0 (waves 8-11, 8 f-loops) -> in_proj phase span 12 -> 8 vs R11.
// Conv / x_proj / scan_sum are identical to R11 (extra waves idle there).
// ---------------------------------------------------------------------------
__global__ __launch_bounds__(768) void k_front(
    const float* __restrict__ xin, const float* __restrict__ lnwL,
    const float* __restrict__ lnbL, const ushort* __restrict__ ipwL,
    const float* __restrict__ cwL, const float* __restrict__ cbL,
    const ushort* __restrict__ xpwL, const float* __restrict__ dpwL,
    const float* __restrict__ dpbL, const float* __restrict__ alogL,
    ushort* __restrict__ zsB, ushort* __restrict__ xcB,
    float* __restrict__ dbl, float* __restrict__ Ssum,
    float* __restrict__ sdsum)
{
    const int t = threadIdx.x, bid = blockIdx.x;
    const int lane = t & 63, w = t >> 6, l15 = lane & 15, quad = lane >> 4;
    __shared__ float  xs[19 * XS_STR];     // 19.8 KB
    __shared__ ushort hs[19 * HS_STR];     // 10.0 KB
    __shared__ ushort xi_s[19 * 512];      // 19.5 KB  rows: m0-3 .. m0+15
    __shared__ ushort xc_s[16 * XC_STR];   // 16.6 KB
    __shared__ float  dbl_s[16 * 52];      //  3.3 KB
    int m0 = bid * 16;

    // ---- stage x rows m0-3 .. m0+15 (clamp row<0; batch masking via conv) --
    for (int i = t; i < 19 * 64; i += 768) {
        int r = i >> 6, c = (i & 63) * 4;
        int grow = m0 - 3 + r; if (grow < 0) grow = 0;
        float4 v = *(const float4*)(xin + (size_t)grow * D_MODEL + c);
        *(float4*)&xs[r * XS_STR + c] = v;
    }
    __syncthreads();

    // ---- LayerNorm, 19 rows x 16 threads ----
    if (t < 19 * 16) {
        int r = t >> 4, ci = t & 15;
        float s = 0.f, sq = 0.f;
        #pragma unroll
        for (int k = 0; k < 16; k++) {
            float v = xs[r * XS_STR + ci + 16 * k];
            s += v; sq += v * v;
        }
        #pragma unroll
        for (int off = 1; off < 16; off <<= 1) {
            s  += __shfl_xor(s, off, 16);
            sq += __shfl_xor(sq, off, 16);
        }
        float mu  = s * (1.0f / 256.f);
        float var = sq * (1.0f / 256.f) - mu * mu;
        float rst = rsqrtf(var + 1e-5f);
        #pragma unroll
        for (int k = 0; k < 16; k++) {
            int c = ci + 16 * k;
            float v = (xs[r * XS_STR + c] - mu) * rst * lnwL[c] + lnbL[c];
            hs[r * HS_STR + c] = f2bf(v);
        }
    }
    __syncthreads();

    // ---- in_proj MFMA, both tiles concurrent ----
    if (w < 8) {
        // tile1: rows m0..m0+15, all 1024 n. n<512 -> xi_s, n>=512 -> zsB.
        #pragma unroll
        for (int f = 0; f < 8; f++) {
            int n = w * 128 + f * 16 + l15;
            f32x4 acc = (f32x4){0.f, 0.f, 0.f, 0.f};
            for (int k0 = 0; k0 < D_MODEL; k0 += 32) {
                bf16x8 af = *(const bf16x8*)&hs[(3 + l15) * HS_STR + quad * 8 + k0];
                bf16x8 bw = *(const bf16x8*)(ipwL + (size_t)n * D_MODEL + quad * 8 + k0);
                acc = __builtin_amdgcn_mfma_f32_16x16x32_bf16(af, bw, acc, 0, 0, 0);
            }
            #pragma unroll
            for (int r2 = 0; r2 < 4; r2++) {
                int rl = quad * 4 + r2;
                if (n < 512) xi_s[(3 + rl) * 512 + n] = f2bf(acc[r2]);
                else zsB[(size_t)(m0 + rl) * D_INNER + (n - 512)] = f2bf(silu(acc[r2]));
            }
        }
    } else {
        // tile0: rows m0-3..m0+12 (keep halo rows 0..2), n<512.
        #pragma unroll
        for (int f = 0; f < 8; f++) {
            int n0 = (w - 8) * 128 + f * 16;
            f32x4 acc = (f32x4){0.f, 0.f, 0.f, 0.f};
            for (int k0 = 0; k0 < D_MODEL; k0 += 32) {
                bf16x8 af = *(const bf16x8*)&hs[l15 * HS_STR + quad * 8 + k0];
                bf16x8 bw = *(const bf16x8*)(ipwL + (size_t)(n0 + l15) * D_MODEL + quad * 8 + k0);
                acc = __builtin_amdgcn_mfma_f32_16x16x32_bf16(af, bw, acc, 0, 0, 0);
            }
            if (quad == 0) {
                #pragma unroll
                for (int r2 = 0; r2 < 3; r2++)
                    xi_s[r2 * 512 + n0 + l15] = f2bf(acc[r2]);
            }
        }
    }
    __syncthreads();

    // ---- conv(4) + SiLU -> xc_s + xcB. d = t (threads 0..511) ----
    if (t < 512) {
        float4 cw4 = *(const float4*)(cwL + t * 4);
        float cbv = cbL[t];
        #pragma unroll
        for (int rl = 0; rl < 16; rl++) {
            int l = (m0 + rl) & (SEQLEN - 1);
            float s = cbv;
            if (l >= 3) s = fmaf(cw4.x, bf2f(xi_s[(rl + 0) * 512 + t]), s);
            if (l >= 2) s = fmaf(cw4.y, bf2f(xi_s[(rl + 1) * 512 + t]), s);
            if (l >= 1) s = fmaf(cw4.z, bf2f(xi_s[(rl + 2) * 512 + t]), s);
            s = fmaf(cw4.w, bf2f(xi_s[(rl + 3) * 512 + t]), s);
            ushort xcv = f2bf(silu(s));
            xc_s[rl * XC_STR + t] = xcv;
            xcB[(size_t)(m0 + rl) * D_INNER + t] = xcv;
        }
    }
    __syncthreads();

    // ---- x_proj MFMA (waves 0..2, one 16-n tile each) ----
    if (w < 3) {
        f32x4 acc = (f32x4){0.f, 0.f, 0.f, 0.f};
        for (int k0 = 0; k0 < D_INNER; k0 += 32) {
            bf16x8 af = *(const bf16x8*)&xc_s[l15 * XC_STR + quad * 8 + k0];
            bf16x8 bw = *(const bf16x8*)(xpwL + (size_t)(w * 16 + l15) * D_INNER + quad * 8 + k0);
            acc = __builtin_amdgcn_mfma_f32_16x16x32_bf16(af, bw, acc, 0, 0, 0);
        }
        int n = w * 16 + l15;
        #pragma unroll
        for (int r2 = 0; r2 < 4; r2++) {
            int rl = quad * 4 + r2;
            dbl_s[rl * 52 + n] = acc[r2];
            dbl[(size_t)(m0 + rl) * 48 + n] = acc[r2];
        }
    }
    __syncthreads();

    // ---- scan_sum (d = t, threads 0..511), delta inline from dbl_s ----
    if (t < 512) {
        float a[16], wdp[16];
        #pragma unroll
        for (int n = 0; n < 16; n++) a[n] = -__expf(alogL[(size_t)t * 16 + n]);
        *(float4*)&wdp[0]  = *(const float4*)(dpwL + (size_t)t * 16 + 0);
        *(float4*)&wdp[4]  = *(const float4*)(dpwL + (size_t)t * 16 + 4);
        *(float4*)&wdp[8]  = *(const float4*)(dpwL + (size_t)t * 16 + 8);
        *(float4*)&wdp[12] = *(const float4*)(dpwL + (size_t)t * 16 + 12);
        float bias = dpbL[t];
        float h[16];
        #pragma unroll
        for (int n = 0; n < 16; n++) h[n] = 0.f;
        float sd = 0.f;
        for (int j = 0; j < LCH; j++) {
            const float* dp = &dbl_s[j * 52];
            float dot = bias;
            #pragma unroll
            for (int r2 = 0; r2 < 16; r2++) dot = fmaf(dp[r2], wdp[r2], dot);
            float dl = (dot > 20.f) ? dot : log1pf(__expf(dot));
            float xv = bf2f(xc_s[j * XC_STR + t]);
            float u = dl * xv;
            sd += dl;
            #pragma unroll
            for (int n = 0; n < 16; n++)
                h[n] = fmaf(__expf(dl * a[n]), h[n], dp[16 + n] * u);
        }
        size_t sbase = ((size_t)bid * 16) * D_INNER + t;
        #pragma unroll
        for (int n = 0; n < 16; n++) Ssum[sbase + (size_t)n * D_INNER] = h[n];
        sdsum[(size_t)bid * D_INNER + t] = sd;
    }
}

// ---------------------------------------------------------------------------
// k_comb: in-place exclusive prefix over chunk summaries. Grid 64.
// ---------------------------------------------------------------------------
__global__ __launch_bounds__(256) void k_comb(
    const float* __restrict__ alogL, const float* __restrict__ sdsum,
    float* __restrict__ Ssum)
{
    const int t = threadIdx.x, bid = blockIdx.x;
    int dt2 = bid & 1;
    int n   = (bid >> 1) & 15;
    int b   = bid >> 5;
    int d   = dt2 * 256 + t;
    float a = -__expf(alogL[(size_t)d * 16 + n]);
    float hi = 0.f;
    #pragma unroll 4
    for (int c = 0; c < CCH; c++) {
        size_t idx = ((size_t)(b * CCH + c) * 16 + n) * D_INNER + d;
        float s  = Ssum[idx];
        float sd = sdsum[(size_t)(b * CCH + c) * D_INNER + d];
        Ssum[idx] = hi;
        hi = fmaf(__expf(a * sd), hi, s);
    }
}

// ---------------------------------------------------------------------------
// k_back: rescan from true h_init (delta inline) + D-skip + SiLU(z) gate,
//         yy kept in LDS, then out_proj MFMA + residual. Grid 256 x 512.
// ---------------------------------------------------------------------------
__global__ __launch_bounds__(512) void k_back(
    const float* __restrict__ dbl, const ushort* __restrict__ xcB,
    const ushort* __restrict__ zsB, const float* __restrict__ Ssum,
    const float* __restrict__ dpwL, const float* __restrict__ dpbL,
    const float* __restrict__ alogL, const float* __restrict__ dparL,
    const ushort* __restrict__ opwL, const float* __restrict__ xin,
    float* __restrict__ xout)
{
    const int t = threadIdx.x, bid = blockIdx.x;
    const int lane = t & 63, w = t >> 6, l15 = lane & 15, quad = lane >> 4;
    __shared__ ushort yy_s[16 * XC_STR];   // 16.6 KB
    int m0 = bid * 16;

    // ---- rescan, d = t ----
    {
        float a[16], wdp[16];
        #pragma unroll
        for (int n = 0; n < 16; n++) a[n] = -__expf(alogL[(size_t)t * 16 + n]);
        *(float4*)&wdp[0]  = *(const float4*)(dpwL + (size_t)t * 16 + 0);
        *(float4*)&wdp[4]  = *(const float4*)(dpwL + (size_t)t * 16 + 4);
        *(float4*)&wdp[8]  = *(const float4*)(dpwL + (size_t)t * 16 + 8);
        *(float4*)&wdp[12] = *(const float4*)(dpwL + (size_t)t * 16 + 12);
        float bias = dpbL[t];
        float Dd = dparL[t];
        float h[16];
        size_t sbase = ((size_t)bid * 16) * D_INNER + t;
        #pragma unroll
        for (int n = 0; n < 16; n++) h[n] = Ssum[sbase + (size_t)n * D_INNER];
        for (int j = 0; j < LCH; j++) {
            int row = m0 + j;
            const float* dp = dbl + (size_t)row * 48;
            float dtv[16], Bv[16], Cv[16];
            *(float4*)&dtv[0]  = *(const float4*)(dp + 0);
            *(float4*)&dtv[4]  = *(const float4*)(dp + 4);
            *(float4*)&dtv[8]  = *(const float4*)(dp + 8);
            *(float4*)&dtv[12] = *(const float4*)(dp + 12);
            *(float4*)&Bv[0]   = *(const float4*)(dp + 16);
            *(float4*)&Bv[4]   = *(const float4*)(dp + 20);
            *(float4*)&Bv[8]   = *(const float4*)(dp + 24);
            *(float4*)&Bv[12]  = *(const float4*)(dp + 28);
            *(float4*)&Cv[0]   = *(const float4*)(dp + 32);
            *(float4*)&Cv[4]   = *(const float4*)(dp + 36);
            *(float4*)&Cv[8]   = *(const float4*)(dp + 40);
            *(float4*)&Cv[12]  = *(const float4*)(dp + 44);
            float dot = bias;
            #pragma unroll
            for (int r2 = 0; r2 < 16; r2++) dot = fmaf(dtv[r2], wdp[r2], dot);
            float dl = (dot > 20.f) ? dot : log1pf(__expf(dot));
            float xv = bf2f(xcB[(size_t)row * D_INNER + t]);
            float gate = bf2f(zsB[(size_t)row * D_INNER + t]);
            float u = dl * xv;
            float y0 = 0.f, y1 = 0.f, y2 = 0.f, y3 = 0.f;
            #pragma unroll
            for (int n = 0; n < 16; n += 4) {
                h[n + 0] = fmaf(__expf(dl * a[n + 0]), h[n + 0], Bv[n + 0] * u);
                h[n + 1] = fmaf(__expf(dl * a[n + 1]), h[n + 1], Bv[n + 1] * u);
                h[n + 2] = fmaf(__expf(dl * a[n + 2]), h[n + 2], Bv[n + 2] * u);
                h[n + 3] = fmaf(__expf(dl * a[n + 3]), h[n + 3], Bv[n + 3] * u);
                y0 = fmaf(h[n + 0], Cv[n + 0], y0);
                y1 = fmaf(h[n + 1], Cv[n + 1], y1);
                y2 = fmaf(h[n + 2], Cv[n + 2], y2);
                y3 = fmaf(h[n + 3], Cv[n + 3], y3);
            }
            float y = (y0 + y1) + (y2 + y3) + xv * Dd;
            yy_s[j * XC_STR + t] = f2bf(y * gate);
        }
    }
    __syncthreads();

    // ---- out_proj MFMA + residual: wave w -> n-tiles w*32, w*32+16 ----
    #pragma unroll
    for (int f = 0; f < 2; f++) {
        int n = w * 32 + f * 16 + l15;
        f32x4 acc = (f32x4){0.f, 0.f, 0.f, 0.f};
        for (int k0 = 0; k0 < D_INNER; k0 += 32) {
            bf16x8 af = *(const bf16x8*)&yy_s[l15 * XC_STR + quad * 8 + k0];
            bf16x8 bw = *(const bf16x8*)(opwL + (size_t)n * D_INNER + quad * 8 + k0);
            acc = __builtin_amdgcn_mfma_f32_16x16x32_bf16(af, bw, acc, 0, 0, 0);
        }
        #pragma unroll
        for (int r2 = 0; r2 < 4; r2++) {
            int row = m0 + quad * 4 + r2;
            xout[(size_t)row * D_MODEL + n] =
                acc[r2] + xin[(size_t)row * D_MODEL + n];
        }
    }
}

// ---------------------------------------------------------------------------
// Launch
// ---------------------------------------------------------------------------
extern "C" void kernel_launch(void* const* d_in, const int* in_sizes, int n_in,
                              void* d_out, int out_size, void* d_ws, size_t ws_size,
                              hipStream_t stream)
{
    const float* x    = (const float*)d_in[0];
    const float* lnw  = (const float*)d_in[1];
    const float* lnb  = (const float*)d_in[2];
    const float* ipw  = (const float*)d_in[3];
    const float* cw   = (const float*)d_in[4];
    const float* cb   = (const float*)d_in[5];
    const float* xpw  = (const float*)d_in[6];
    const float* dpw  = (const float*)d_in[7];
    const float* dpb  = (const float*)d_in[8];
    const float* alog = (const float*)d_in[9];
    const float* dpar = (const float*)d_in[10];
    const float* opw  = (const float*)d_in[11];
    float* out = (float*)d_out;

    char* p = (char*)d_ws;
    auto alloc = [&](size_t bytes) { char* r = p; p += (bytes + 255) & ~(size_t)255; return r; };
    ushort* zsB   = (ushort*)alloc((size_t)MROWS * D_INNER * 2);
    ushort* xcB   = (ushort*)alloc((size_t)MROWS * D_INNER * 2);
    float*  dbl   = (float*)alloc((size_t)MROWS * 48 * 4);
    float*  Ssum  = (float*)alloc((size_t)BATCH * CCH * 16 * D_INNER * 4);
    float*  sdsum = (float*)alloc((size_t)BATCH * CCH * D_INNER * 4);
    float*  xbuf  = (float*)alloc((size_t)MROWS * D_MODEL * 4);
    ushort* ipwB  = (ushort*)alloc((size_t)DEPTH * 2 * D_INNER * D_MODEL * 2);
    ushort* xpwB  = (ushort*)alloc((size_t)DEPTH * 48 * D_INNER * 2);
    ushort* opwB  = (ushort*)alloc((size_t)DEPTH * D_MODEL * D_INNER * 2);

    k_cvt<<<512, 256, 0, stream>>>(ipw, xpw, opw, ipwB, xpwB, opwB);

    for (int lyr = 0; lyr < DEPTH; lyr++) {
        const float* xin = (lyr == 0) ? x : xbuf;
        float* xout = (lyr == DEPTH - 1) ? out : xbuf;
        const float* alogL = alog + (size_t)lyr * D_INNER * D_STATE;
        const float* dpwL  = dpw + (size_t)lyr * D_INNER * DT_RANK;
        const float* dpbL  = dpb + lyr * D_INNER;

        k_front<<<256, 768, 0, stream>>>(
            xin, lnw + lyr * D_MODEL, lnb + lyr * D_MODEL,
            ipwB + (size_t)lyr * 2 * D_INNER * D_MODEL,
            cw + (size_t)lyr * D_INNER * D_CONV, cb + lyr * D_INNER,
            xpwB + (size_t)lyr * 48 * D_INNER, dpwL, dpbL, alogL,
            zsB, xcB, dbl, Ssum, sdsum);

        k_comb<<<64, 256, 0, stream>>>(alogL, sdsum, Ssum);

        k_back<<<256, 512, 0, stream>>>(
            dbl, xcB, zsB, Ssum, dpwL, dpbL, alogL,
            dpar + lyr * D_INNER,
            opwB + (size_t)lyr * D_MODEL * D_INNER, xin, xout);
    }
}